// Round 1
// baseline (103.857 us; speedup 1.0000x reference)
//
#include <hip/hip_runtime.h>
#include <hip/hip_bf16.h>

// Gram-Schmidt (8192, 32, 256) fp32 via Gram matrix, all-MFMA, fully
// independent waves: one 64-thread block = one wave, PRIVATE 20KB LDS slice
// (16K X bf16 swizzled + 4K W). Zero __syncthreads.
//   stream X HBM -> own LDS (once)  ->  G = X X^T (16 MFMA)  ->
//   lane-packed recurrence -> W (LDS)  ->  Y = (Whi+Wlo) X, 8 chunks,
//   nt-stores.  8 blocks/CU (160KB LDS exactly) = 8 uncorrelated pipelines.
// R16 (this round): PERSISTENT blocks — 2048 blocks x 4 contiguous batches
// per wave. Removes the per-batch dispatch/drain bubble (Occupancy 19.7% vs
// structural 25%): store(i) -> load(i+1) are back-to-back in one wave, the
// HBM queue never drains between batches. LDS X/W reuse across iterations is
// safe via same-wave in-order DS execution (no barrier needed).

#define KDIM 32
#define LDIM 256
#define BPB  4          // batches per persistent block (8192/2048)

typedef __attribute__((ext_vector_type(8)))  short  short8v;   // 8 bf16
typedef __attribute__((ext_vector_type(16))) float  f32x16;    // MFMA acc
typedef __attribute__((ext_vector_type(4)))  unsigned short ushort4v;

__device__ __forceinline__ float RL(float v, int j) {
    return __int_as_float(__builtin_amdgcn_readlane(__float_as_int(v), j));
}
__device__ __forceinline__ unsigned short f2bf(float f) {
    __hip_bfloat16 h = __float2bfloat16(f);
    return *reinterpret_cast<unsigned short*>(&h);
}
__device__ __forceinline__ float bf2f(unsigned short u) {
    return __int_as_float(((int)u) << 16);
}
__device__ __forceinline__ int pk2(float lo, float hi) {
    return (int)f2bf(lo) | ((int)f2bf(hi) << 16);
}

// ---- recurrence (verified R8-R15) ----
#define P2T(I, K) { float ch = RL(v##K, (I)); vA = fmaf(-ch, v##K, vA); }
#define Q0(I)
#define Q1(I)  Q0(I)  P2T(I, 0)
#define Q2(I)  Q1(I)  P2T(I, 1)
#define Q3(I)  Q2(I)  P2T(I, 2)
#define Q4(I)  Q3(I)  P2T(I, 3)
#define Q5(I)  Q4(I)  P2T(I, 4)
#define Q6(I)  Q5(I)  P2T(I, 5)
#define Q7(I)  Q6(I)  P2T(I, 6)
#define Q8(I)  Q7(I)  P2T(I, 7)
#define Q9(I)  Q8(I)  P2T(I, 8)
#define Q10(I) Q9(I)  P2T(I, 9)
#define Q11(I) Q10(I) P2T(I, 10)
#define Q12(I) Q11(I) P2T(I, 11)
#define Q13(I) Q12(I) P2T(I, 12)
#define Q14(I) Q13(I) P2T(I, 13)
#define Q15(I) Q14(I) P2T(I, 14)
#define Q16(I) Q15(I) P2T(I, 15)
#define Q17(I) Q16(I) P2T(I, 16)
#define Q18(I) Q17(I) P2T(I, 17)
#define Q19(I) Q18(I) P2T(I, 18)
#define Q20(I) Q19(I) P2T(I, 19)
#define Q21(I) Q20(I) P2T(I, 20)
#define Q22(I) Q21(I) P2T(I, 21)
#define Q23(I) Q22(I) P2T(I, 22)
#define Q24(I) Q23(I) P2T(I, 23)
#define Q25(I) Q24(I) P2T(I, 24)
#define Q26(I) Q25(I) P2T(I, 25)
#define Q27(I) Q26(I) P2T(I, 26)
#define Q28(I) Q27(I) P2T(I, 27)
#define Q29(I) Q28(I) P2T(I, 28)
#define Q30(I) Q29(I) P2T(I, 29)
#define Q31(I) Q30(I) P2T(I, 30)

// G symmetric: column I == row I; acc reg RI, source lanes HI*32+col
// (C/D layout col=lane&31, row=(r&3)+8(r>>2)+4(lane>>5); verified R6-R15).
#define P2STEP(I, QL, RI, HI) { \
    float gc = __int_as_float(__builtin_amdgcn_ds_bpermute( \
                   (l31 << 2) + ((HI) << 7), __float_as_int(g[RI]))); \
    float vA = ishi ? ((l31 == (I)) ? 1.0f : 0.0f) : gc; \
    QL(I) \
    float d  = RL(vA, (I)); \
    float rn = __builtin_amdgcn_rsqf(d); \
    v##I = vA * rn; }

#define REP32(F) F(0) F(1) F(2) F(3) F(4) F(5) F(6) F(7) F(8) F(9) F(10) F(11) \
                 F(12) F(13) F(14) F(15) F(16) F(17) F(18) F(19) F(20) F(21) F(22) \
                 F(23) F(24) F(25) F(26) F(27) F(28) F(29) F(30) F(31)
#define DECL_V(N) float v##N;
// W row N (lanes 32-63 hold w half); XOR-swizzled (verified R9)
#define STW(N) *(float*)(Wl + (N) * 128 + (((unsigned)(l31 << 2)) ^ ((((N) & 7u)) << 4))) = v##N;

// ---- apply: one 32-col chunk, D = (Whi + Wlo) * X_c, nt-store (verified R9/R15) ----
__device__ __forceinline__ void do_chunk(const char* Xl, float* __restrict__ op0,
                                         int c, int l31, int h8,
                                         short8v ahi0, short8v ahi1,
                                         short8v alo0, short8v alo1) {
    const char* bp = Xl + (h8 << 12);
    const unsigned cb = ((unsigned)c << 6) + ((unsigned)l31 << 1);
    int4 B0, B1;
    {
        unsigned short e0 = *(const unsigned short*)(bp + (cb ^ 0u));
        unsigned short e1 = *(const unsigned short*)(bp + (cb ^ 16u) + 512);
        unsigned short e2 = *(const unsigned short*)(bp + (cb ^ 32u) + 1024);
        unsigned short e3 = *(const unsigned short*)(bp + (cb ^ 48u) + 1536);
        unsigned short e4 = *(const unsigned short*)(bp + (cb ^ 64u) + 2048);
        unsigned short e5 = *(const unsigned short*)(bp + (cb ^ 80u) + 2560);
        unsigned short e6 = *(const unsigned short*)(bp + (cb ^ 96u) + 3072);
        unsigned short e7 = *(const unsigned short*)(bp + (cb ^ 112u) + 3584);
        B0.x = (int)e0 | ((int)e1 << 16);
        B0.y = (int)e2 | ((int)e3 << 16);
        B0.z = (int)e4 | ((int)e5 << 16);
        B0.w = (int)e6 | ((int)e7 << 16);
    }
    {
        unsigned short e0 = *(const unsigned short*)(bp + (cb ^ 0u)   + 8192);
        unsigned short e1 = *(const unsigned short*)(bp + (cb ^ 16u)  + 8704);
        unsigned short e2 = *(const unsigned short*)(bp + (cb ^ 32u)  + 9216);
        unsigned short e3 = *(const unsigned short*)(bp + (cb ^ 48u)  + 9728);
        unsigned short e4 = *(const unsigned short*)(bp + (cb ^ 64u)  + 10240);
        unsigned short e5 = *(const unsigned short*)(bp + (cb ^ 80u)  + 10752);
        unsigned short e6 = *(const unsigned short*)(bp + (cb ^ 96u)  + 11264);
        unsigned short e7 = *(const unsigned short*)(bp + (cb ^ 112u) + 11776);
        B1.x = (int)e0 | ((int)e1 << 16);
        B1.y = (int)e2 | ((int)e3 << 16);
        B1.z = (int)e4 | ((int)e5 << 16);
        B1.w = (int)e6 | ((int)e7 << 16);
    }
    short8v b0 = *reinterpret_cast<short8v*>(&B0);
    short8v b1 = *reinterpret_cast<short8v*>(&B1);
    f32x16 d = {0.f,0.f,0.f,0.f, 0.f,0.f,0.f,0.f, 0.f,0.f,0.f,0.f, 0.f,0.f,0.f,0.f};
    d = __builtin_amdgcn_mfma_f32_32x32x16_bf16(alo0, b0, d, 0, 0, 0);
    d = __builtin_amdgcn_mfma_f32_32x32x16_bf16(alo1, b1, d, 0, 0, 0);
    d = __builtin_amdgcn_mfma_f32_32x32x16_bf16(ahi0, b0, d, 0, 0, 0);
    d = __builtin_amdgcn_mfma_f32_32x32x16_bf16(ahi1, b1, d, 0, 0, 0);
    float* op = op0 + (c << 5) + l31;
#pragma unroll
    for (int r = 0; r < 16; ++r) {
        int row = (r & 3) + 8 * (r >> 2) + (h8 << 2);
        __builtin_nontemporal_store(d[r], op + row * 256);
    }
}

// A-frag window M from LDS W: lane needs W[l31][16M + 8*h8 + j], hi/lo split (verified R9)
#define MKFRAG(M, AHI, ALO) { \
    unsigned bo = 64u * (M) + ((unsigned)h8 << 5); \
    float4 fa = *(const float4*)(Wl + arow * 128 + (bo ^ sw)); \
    float4 fb = *(const float4*)(Wl + arow * 128 + ((bo + 16u) ^ sw)); \
    unsigned short hh0 = f2bf(fa.x), hh1 = f2bf(fa.y), hh2 = f2bf(fa.z), hh3 = f2bf(fa.w); \
    unsigned short hh4 = f2bf(fb.x), hh5 = f2bf(fb.y), hh6 = f2bf(fb.z), hh7 = f2bf(fb.w); \
    int4 HI_, LO_; \
    HI_.x = (int)hh0 | ((int)hh1 << 16); HI_.y = (int)hh2 | ((int)hh3 << 16); \
    HI_.z = (int)hh4 | ((int)hh5 << 16); HI_.w = (int)hh6 | ((int)hh7 << 16); \
    LO_.x = pk2(fa.x - bf2f(hh0), fa.y - bf2f(hh1)); \
    LO_.y = pk2(fa.z - bf2f(hh2), fa.w - bf2f(hh3)); \
    LO_.z = pk2(fb.x - bf2f(hh4), fb.y - bf2f(hh5)); \
    LO_.w = pk2(fb.z - bf2f(hh6), fb.w - bf2f(hh7)); \
    AHI = *reinterpret_cast<short8v*>(&HI_); \
    ALO = *reinterpret_cast<short8v*>(&LO_); }

// store one fp32 row r of X into bf16 swizzled LDS buffer (verified layout)
__device__ __forceinline__ void put_row(char* __restrict__ Xl, int r, int lane, float4 v) {
    ushort4v u;
    u.x = f2bf(v.x); u.y = f2bf(v.y); u.z = f2bf(v.z); u.w = f2bf(v.w);
    *(ushort4v*)(Xl + ((((unsigned)r << 9) + ((unsigned)lane << 3)) ^ (((unsigned)r & 7u) << 4))) = u;
}

// G = X X^T (MFMA) + recurrence + stage W  (verified R9; fits 84 VGPR per R15)
__device__ __forceinline__ void compute_W(const char* __restrict__ Xl,
                                          char* __restrict__ Wl,
                                          int lane, int l31, bool ishi) {
    f32x16 g = {0.f,0.f,0.f,0.f, 0.f,0.f,0.f,0.f, 0.f,0.f,0.f,0.f, 0.f,0.f,0.f,0.f};
    {
        const unsigned abase = ((unsigned)l31 << 9) + (((unsigned)lane >> 5) << 4);
        const unsigned swz   = ((unsigned)(l31 & 7)) << 4;
#pragma unroll
        for (int t = 0; t < 16; ++t) {
            short8v f = *(const short8v*)(Xl + ((abase + (unsigned)t * 32u) ^ swz));
            g = __builtin_amdgcn_mfma_f32_32x32x16_bf16(f, f, g, 0, 0, 0);
        }
    }
    REP32(DECL_V)
    P2STEP(0,  Q0,  0,  0) P2STEP(1,  Q1,  1,  0) P2STEP(2,  Q2,  2,  0) P2STEP(3,  Q3,  3,  0)
    P2STEP(4,  Q4,  0,  1) P2STEP(5,  Q5,  1,  1) P2STEP(6,  Q6,  2,  1) P2STEP(7,  Q7,  3,  1)
    P2STEP(8,  Q8,  4,  0) P2STEP(9,  Q9,  5,  0) P2STEP(10, Q10, 6,  0) P2STEP(11, Q11, 7,  0)
    P2STEP(12, Q12, 4,  1) P2STEP(13, Q13, 5,  1) P2STEP(14, Q14, 6,  1) P2STEP(15, Q15, 7,  1)
    P2STEP(16, Q16, 8,  0) P2STEP(17, Q17, 9,  0) P2STEP(18, Q18, 10, 0) P2STEP(19, Q19, 11, 0)
    P2STEP(20, Q20, 8,  1) P2STEP(21, Q21, 9,  1) P2STEP(22, Q22, 10, 1) P2STEP(23, Q23, 11, 1)
    P2STEP(24, Q24, 12, 0) P2STEP(25, Q25, 13, 0) P2STEP(26, Q26, 14, 0) P2STEP(27, Q27, 15, 0)
    P2STEP(28, Q28, 12, 1) P2STEP(29, Q29, 13, 1) P2STEP(30, Q30, 14, 1) P2STEP(31, Q31, 15, 1)
    if (ishi) { REP32(STW) }
}

__global__ __launch_bounds__(64)     // one wave per block; 8 x 20KB = 160KB/CU exactly
void gs_kernel(const float* __restrict__ x, float* __restrict__ out, int nbatch) {
    __shared__ char smem[20480];     // X bf16 16K | W fp32 4K  (private to this wave)
    const int lane = threadIdx.x;    // 0..63
    const int l31  = lane & 31;
    const int h8   = lane >> 5;
    const bool ishi = h8 != 0;

    char* Xl = smem;
    char* Wl = smem + 16384;

    const long b0   = (long)blockIdx.x * BPB;
    if (b0 >= nbatch) return;
    long bend = b0 + BPB;
    if (bend > nbatch) bend = nbatch;

    const int arow = l31;
    const unsigned sw = ((unsigned)(arow & 7)) << 4;

    // persistent loop: 4 contiguous batches per wave. store(i) -> load(i+1)
    // back-to-back; LDS reuse safe via same-wave in-order DS execution.
#pragma unroll 1
    for (long b = b0; b < bend; ++b) {
        const float4* __restrict__ xg = reinterpret_cast<const float4*>(x) + b * (KDIM * 64);
        float* __restrict__ outF      = out + b * (KDIM * LDIM);

        // ---- stream X once: HBM -> private bf16 LDS (same-wave ordering, no barrier) ----
#pragma unroll
        for (int r = 0; r < KDIM; ++r) {
            put_row(Xl, r, lane, xg[r * 64 + lane]);
        }

        // ---- G + recurrence + W stage (wave-local) ----
        compute_W(Xl, Wl, lane, l31, ishi);

        // ---- apply: Y = (Whi+Wlo) X, all 8 chunks, nt-stores ----
        short8v ahi0, alo0, ahi1, alo1;
        MKFRAG(0, ahi0, alo0)
        MKFRAG(1, ahi1, alo1)
#pragma unroll
        for (int c = 0; c < 8; ++c) {
            do_chunk(Xl, outF, c, l31, h8, ahi0, ahi1, alo0, alo1);
        }
    }
}

extern "C" void kernel_launch(void* const* d_in, const int* in_sizes, int n_in,
                              void* d_out, int out_size, void* d_ws, size_t ws_size,
                              hipStream_t stream) {
    const float* x = (const float*)d_in[0];
    float* out     = (float*)d_out;
    const int nbatch = in_sizes[0] / (KDIM * LDIM);   // 8192
    const int nblocks = (nbatch + BPB - 1) / BPB;     // 2048 = 8 blocks/CU exactly
    gs_kernel<<<nblocks, 64, 0, stream>>>(x, out, nbatch);
}

// Round 2
// 91.807 us; speedup vs baseline: 1.1312x; 1.1312x over previous
//
#include <hip/hip_runtime.h>
#include <hip/hip_bf16.h>

// Gram-Schmidt (8192, 32, 256) fp32 via Gram matrix, all-MFMA, fully
// independent waves: one 64-thread block = one wave = one batch, with a
// PRIVATE 20KB LDS slice (16K X bf16 swizzled + 4K W). Zero __syncthreads.
//   stream X HBM -> own LDS (once)  ->  G = X X^T (16 MFMA)  ->
//   lane-packed recurrence -> W (LDS)  ->  Y = (Whi+Wlo) X, 8 chunks,
//   nt-stores.  8 blocks/CU (160KB LDS exactly) = 8 uncorrelated pipelines.
// R8-R15 lesson: every barrier-coupled structure idles most waves most of
// the time (util ~11%); the only barrier-free design (R13) had the best
// effective BW but doubled FETCH by re-reading X from global.
// R16 lesson (REVERTED here): persistent 2048-block x 4-batch grid removed
// the HW dispatcher's dynamic load-balancing; occupancy HALVED (19.7->10.4%)
// and dur regressed 91->104 us. The per-batch dispatch "bubble" theory was
// wrong — HW backfill IS the load balancer. Keep 8192 independent blocks.
// Data plane at 91.2 us = 5.89 TB/s = 93.5% of the 6.29 TB/s copy ceiling.

#define KDIM 32
#define LDIM 256

typedef __attribute__((ext_vector_type(8)))  short  short8v;   // 8 bf16
typedef __attribute__((ext_vector_type(16))) float  f32x16;    // MFMA acc
typedef __attribute__((ext_vector_type(4)))  unsigned short ushort4v;

__device__ __forceinline__ float RL(float v, int j) {
    return __int_as_float(__builtin_amdgcn_readlane(__float_as_int(v), j));
}
__device__ __forceinline__ unsigned short f2bf(float f) {
    __hip_bfloat16 h = __float2bfloat16(f);
    return *reinterpret_cast<unsigned short*>(&h);
}
__device__ __forceinline__ float bf2f(unsigned short u) {
    return __int_as_float(((int)u) << 16);
}
__device__ __forceinline__ int pk2(float lo, float hi) {
    return (int)f2bf(lo) | ((int)f2bf(hi) << 16);
}

// ---- recurrence (verified R8-R15) ----
#define P2T(I, K) { float ch = RL(v##K, (I)); vA = fmaf(-ch, v##K, vA); }
#define Q0(I)
#define Q1(I)  Q0(I)  P2T(I, 0)
#define Q2(I)  Q1(I)  P2T(I, 1)
#define Q3(I)  Q2(I)  P2T(I, 2)
#define Q4(I)  Q3(I)  P2T(I, 3)
#define Q5(I)  Q4(I)  P2T(I, 4)
#define Q6(I)  Q5(I)  P2T(I, 5)
#define Q7(I)  Q6(I)  P2T(I, 6)
#define Q8(I)  Q7(I)  P2T(I, 7)
#define Q9(I)  Q8(I)  P2T(I, 8)
#define Q10(I) Q9(I)  P2T(I, 9)
#define Q11(I) Q10(I) P2T(I, 10)
#define Q12(I) Q11(I) P2T(I, 11)
#define Q13(I) Q12(I) P2T(I, 12)
#define Q14(I) Q13(I) P2T(I, 13)
#define Q15(I) Q14(I) P2T(I, 14)
#define Q16(I) Q15(I) P2T(I, 15)
#define Q17(I) Q16(I) P2T(I, 16)
#define Q18(I) Q17(I) P2T(I, 17)
#define Q19(I) Q18(I) P2T(I, 18)
#define Q20(I) Q19(I) P2T(I, 19)
#define Q21(I) Q20(I) P2T(I, 20)
#define Q22(I) Q21(I) P2T(I, 21)
#define Q23(I) Q22(I) P2T(I, 22)
#define Q24(I) Q23(I) P2T(I, 23)
#define Q25(I) Q24(I) P2T(I, 24)
#define Q26(I) Q25(I) P2T(I, 25)
#define Q27(I) Q26(I) P2T(I, 26)
#define Q28(I) Q27(I) P2T(I, 27)
#define Q29(I) Q28(I) P2T(I, 28)
#define Q30(I) Q29(I) P2T(I, 29)
#define Q31(I) Q30(I) P2T(I, 30)

// G symmetric: column I == row I; acc reg RI, source lanes HI*32+col
// (C/D layout col=lane&31, row=(r&3)+8(r>>2)+4(lane>>5); verified R6-R15).
#define P2STEP(I, QL, RI, HI) { \
    float gc = __int_as_float(__builtin_amdgcn_ds_bpermute( \
                   (l31 << 2) + ((HI) << 7), __float_as_int(g[RI]))); \
    float vA = ishi ? ((l31 == (I)) ? 1.0f : 0.0f) : gc; \
    QL(I) \
    float d  = RL(vA, (I)); \
    float rn = __builtin_amdgcn_rsqf(d); \
    v##I = vA * rn; }

#define REP32(F) F(0) F(1) F(2) F(3) F(4) F(5) F(6) F(7) F(8) F(9) F(10) F(11) \
                 F(12) F(13) F(14) F(15) F(16) F(17) F(18) F(19) F(20) F(21) F(22) \
                 F(23) F(24) F(25) F(26) F(27) F(28) F(29) F(30) F(31)
#define DECL_V(N) float v##N;
// W row N (lanes 32-63 hold w half); XOR-swizzled (verified R9)
#define STW(N) *(float*)(Wl + (N) * 128 + (((unsigned)(l31 << 2)) ^ ((((N) & 7u)) << 4))) = v##N;

// ---- apply: one 32-col chunk, D = (Whi + Wlo) * X_c, nt-store (verified R9/R15) ----
__device__ __forceinline__ void do_chunk(const char* Xl, float* __restrict__ op0,
                                         int c, int l31, int h8,
                                         short8v ahi0, short8v ahi1,
                                         short8v alo0, short8v alo1) {
    const char* bp = Xl + (h8 << 12);
    const unsigned cb = ((unsigned)c << 6) + ((unsigned)l31 << 1);
    int4 B0, B1;
    {
        unsigned short e0 = *(const unsigned short*)(bp + (cb ^ 0u));
        unsigned short e1 = *(const unsigned short*)(bp + (cb ^ 16u) + 512);
        unsigned short e2 = *(const unsigned short*)(bp + (cb ^ 32u) + 1024);
        unsigned short e3 = *(const unsigned short*)(bp + (cb ^ 48u) + 1536);
        unsigned short e4 = *(const unsigned short*)(bp + (cb ^ 64u) + 2048);
        unsigned short e5 = *(const unsigned short*)(bp + (cb ^ 80u) + 2560);
        unsigned short e6 = *(const unsigned short*)(bp + (cb ^ 96u) + 3072);
        unsigned short e7 = *(const unsigned short*)(bp + (cb ^ 112u) + 3584);
        B0.x = (int)e0 | ((int)e1 << 16);
        B0.y = (int)e2 | ((int)e3 << 16);
        B0.z = (int)e4 | ((int)e5 << 16);
        B0.w = (int)e6 | ((int)e7 << 16);
    }
    {
        unsigned short e0 = *(const unsigned short*)(bp + (cb ^ 0u)   + 8192);
        unsigned short e1 = *(const unsigned short*)(bp + (cb ^ 16u)  + 8704);
        unsigned short e2 = *(const unsigned short*)(bp + (cb ^ 32u)  + 9216);
        unsigned short e3 = *(const unsigned short*)(bp + (cb ^ 48u)  + 9728);
        unsigned short e4 = *(const unsigned short*)(bp + (cb ^ 64u)  + 10240);
        unsigned short e5 = *(const unsigned short*)(bp + (cb ^ 80u)  + 10752);
        unsigned short e6 = *(const unsigned short*)(bp + (cb ^ 96u)  + 11264);
        unsigned short e7 = *(const unsigned short*)(bp + (cb ^ 112u) + 11776);
        B1.x = (int)e0 | ((int)e1 << 16);
        B1.y = (int)e2 | ((int)e3 << 16);
        B1.z = (int)e4 | ((int)e5 << 16);
        B1.w = (int)e6 | ((int)e7 << 16);
    }
    short8v b0 = *reinterpret_cast<short8v*>(&B0);
    short8v b1 = *reinterpret_cast<short8v*>(&B1);
    f32x16 d = {0.f,0.f,0.f,0.f, 0.f,0.f,0.f,0.f, 0.f,0.f,0.f,0.f, 0.f,0.f,0.f,0.f};
    d = __builtin_amdgcn_mfma_f32_32x32x16_bf16(alo0, b0, d, 0, 0, 0);
    d = __builtin_amdgcn_mfma_f32_32x32x16_bf16(alo1, b1, d, 0, 0, 0);
    d = __builtin_amdgcn_mfma_f32_32x32x16_bf16(ahi0, b0, d, 0, 0, 0);
    d = __builtin_amdgcn_mfma_f32_32x32x16_bf16(ahi1, b1, d, 0, 0, 0);
    float* op = op0 + (c << 5) + l31;
#pragma unroll
    for (int r = 0; r < 16; ++r) {
        int row = (r & 3) + 8 * (r >> 2) + (h8 << 2);
        __builtin_nontemporal_store(d[r], op + row * 256);
    }
}

// A-frag window M from LDS W: lane needs W[l31][16M + 8*h8 + j], hi/lo split (verified R9)
#define MKFRAG(M, AHI, ALO) { \
    unsigned bo = 64u * (M) + ((unsigned)h8 << 5); \
    float4 fa = *(const float4*)(Wl + arow * 128 + (bo ^ sw)); \
    float4 fb = *(const float4*)(Wl + arow * 128 + ((bo + 16u) ^ sw)); \
    unsigned short hh0 = f2bf(fa.x), hh1 = f2bf(fa.y), hh2 = f2bf(fa.z), hh3 = f2bf(fa.w); \
    unsigned short hh4 = f2bf(fb.x), hh5 = f2bf(fb.y), hh6 = f2bf(fb.z), hh7 = f2bf(fb.w); \
    int4 HI_, LO_; \
    HI_.x = (int)hh0 | ((int)hh1 << 16); HI_.y = (int)hh2 | ((int)hh3 << 16); \
    HI_.z = (int)hh4 | ((int)hh5 << 16); HI_.w = (int)hh6 | ((int)hh7 << 16); \
    LO_.x = pk2(fa.x - bf2f(hh0), fa.y - bf2f(hh1)); \
    LO_.y = pk2(fa.z - bf2f(hh2), fa.w - bf2f(hh3)); \
    LO_.z = pk2(fb.x - bf2f(hh4), fb.y - bf2f(hh5)); \
    LO_.w = pk2(fb.z - bf2f(hh6), fb.w - bf2f(hh7)); \
    AHI = *reinterpret_cast<short8v*>(&HI_); \
    ALO = *reinterpret_cast<short8v*>(&LO_); }

// store one fp32 row r of X into bf16 swizzled LDS buffer (verified layout)
__device__ __forceinline__ void put_row(char* __restrict__ Xl, int r, int lane, float4 v) {
    ushort4v u;
    u.x = f2bf(v.x); u.y = f2bf(v.y); u.z = f2bf(v.z); u.w = f2bf(v.w);
    *(ushort4v*)(Xl + ((((unsigned)r << 9) + ((unsigned)lane << 3)) ^ (((unsigned)r & 7u) << 4))) = u;
}

// G = X X^T (MFMA) + recurrence + stage W  (verified R9; fits 84 VGPR per R15)
__device__ __forceinline__ void compute_W(const char* __restrict__ Xl,
                                          char* __restrict__ Wl,
                                          int lane, int l31, bool ishi) {
    f32x16 g = {0.f,0.f,0.f,0.f, 0.f,0.f,0.f,0.f, 0.f,0.f,0.f,0.f, 0.f,0.f,0.f,0.f};
    {
        const unsigned abase = ((unsigned)l31 << 9) + (((unsigned)lane >> 5) << 4);
        const unsigned swz   = ((unsigned)(l31 & 7)) << 4;
#pragma unroll
        for (int t = 0; t < 16; ++t) {
            short8v f = *(const short8v*)(Xl + ((abase + (unsigned)t * 32u) ^ swz));
            g = __builtin_amdgcn_mfma_f32_32x32x16_bf16(f, f, g, 0, 0, 0);
        }
    }
    REP32(DECL_V)
    P2STEP(0,  Q0,  0,  0) P2STEP(1,  Q1,  1,  0) P2STEP(2,  Q2,  2,  0) P2STEP(3,  Q3,  3,  0)
    P2STEP(4,  Q4,  0,  1) P2STEP(5,  Q5,  1,  1) P2STEP(6,  Q6,  2,  1) P2STEP(7,  Q7,  3,  1)
    P2STEP(8,  Q8,  4,  0) P2STEP(9,  Q9,  5,  0) P2STEP(10, Q10, 6,  0) P2STEP(11, Q11, 7,  0)
    P2STEP(12, Q12, 4,  1) P2STEP(13, Q13, 5,  1) P2STEP(14, Q14, 6,  1) P2STEP(15, Q15, 7,  1)
    P2STEP(16, Q16, 8,  0) P2STEP(17, Q17, 9,  0) P2STEP(18, Q18, 10, 0) P2STEP(19, Q19, 11, 0)
    P2STEP(20, Q20, 8,  1) P2STEP(21, Q21, 9,  1) P2STEP(22, Q22, 10, 1) P2STEP(23, Q23, 11, 1)
    P2STEP(24, Q24, 12, 0) P2STEP(25, Q25, 13, 0) P2STEP(26, Q26, 14, 0) P2STEP(27, Q27, 15, 0)
    P2STEP(28, Q28, 12, 1) P2STEP(29, Q29, 13, 1) P2STEP(30, Q30, 14, 1) P2STEP(31, Q31, 15, 1)
    if (ishi) { REP32(STW) }
}

__global__ __launch_bounds__(64)     // one wave per block; 8 x 20KB = 160KB/CU exactly
void gs_kernel(const float* __restrict__ x, float* __restrict__ out, int nbatch) {
    __shared__ char smem[20480];     // X bf16 16K | W fp32 4K  (private to this wave)
    const int lane = threadIdx.x;    // 0..63
    const int l31  = lane & 31;
    const int h8   = lane >> 5;
    const bool ishi = h8 != 0;

    const long b = blockIdx.x;
    if (b >= nbatch) return;

    char* Xl = smem;
    char* Wl = smem + 16384;

    const float4* __restrict__ xg = reinterpret_cast<const float4*>(x) + b * (KDIM * 64);
    float* __restrict__ outF      = out + b * (KDIM * LDIM);

    // ---- stream X once: HBM -> private bf16 LDS (same-wave ordering, no barrier) ----
#pragma unroll
    for (int r = 0; r < KDIM; ++r) {
        put_row(Xl, r, lane, xg[r * 64 + lane]);
    }

    // ---- G + recurrence + W stage (wave-local) ----
    compute_W(Xl, Wl, lane, l31, ishi);

    // ---- apply: Y = (Whi+Wlo) X, all 8 chunks, nt-stores ----
    const int arow = l31;
    const unsigned sw = ((unsigned)(arow & 7)) << 4;
    short8v ahi0, alo0, ahi1, alo1;
    MKFRAG(0, ahi0, alo0)
    MKFRAG(1, ahi1, alo1)
#pragma unroll
    for (int c = 0; c < 8; ++c) {
        do_chunk(Xl, outF, c, l31, h8, ahi0, ahi1, alo0, alo1);
    }
}

extern "C" void kernel_launch(void* const* d_in, const int* in_sizes, int n_in,
                              void* d_out, int out_size, void* d_ws, size_t ws_size,
                              hipStream_t stream) {
    const float* x = (const float*)d_in[0];
    float* out     = (float*)d_out;
    const int nbatch = in_sizes[0] / (KDIM * LDIM);   // 8192
    gs_kernel<<<nbatch, 64, 0, stream>>>(x, out, nbatch);
}